// Round 8
// baseline (46.848 us; speedup 1.0000x reference)
//
#include <hip/hip_runtime.h>
#include <stdint.h>

#define N_IMG 16
#define H_DIM 512
#define W_DIM 512
#define PADR 15
#define BAND 16                 // output rows per mega block (2 row-groups x 8)
#define HALO (BAND + 2 * PADR)  // 46 staged bitmap rows
#define WPR 18                  // 32-bit words per row: 1 pad + 16 data + 1 pad
#define NBANDS 32               // H / BAND
#define WROW (W_DIM / 32)       // 16 data words per row

// ws layout (poison-safe: every word written before read, every launch):
//   part @ 0      : 512 blocks * 5 f32  [bce,in0,in1,un0,un1]
//   bm   @ 32 KiB : uint32 bm[N][512][16]  (bit c&31 of word c>>5 = target==1)

// ---------------------------------------------------------------------------
// Stage 1: target -> bit-plane. int4 x2 per thread (8 elems), words assembled
// with 2 shfl_xor OR-merges. 2048 blocks x 256 threads; ~HBM-bound (16.8 MB).
// ---------------------------------------------------------------------------
__global__ __launch_bounds__(256) void bitmap_kernel(const int4* __restrict__ tg4,
                                                     uint32_t* __restrict__ bm) {
    const int tid = threadIdx.x;
    const size_t t = (size_t)blockIdx.x * 256 + tid;   // global thread, 8 ints each
    const int4 a = tg4[t * 2];
    const int4 b = tg4[t * 2 + 1];
    uint32_t by = (uint32_t)(a.x == 1) | ((uint32_t)(a.y == 1) << 1) |
                  ((uint32_t)(a.z == 1) << 2) | ((uint32_t)(a.w == 1) << 3) |
                  ((uint32_t)(b.x == 1) << 4) | ((uint32_t)(b.y == 1) << 5) |
                  ((uint32_t)(b.z == 1) << 6) | ((uint32_t)(b.w == 1) << 7);
    uint32_t w = by << (8 * (tid & 3));
    w |= __shfl_xor(w, 1);
    w |= __shfl_xor(w, 2);
    if ((tid & 3) == 0) bm[t >> 2] = w;
}

// ---------------------------------------------------------------------------
// Stage 2: fused 31x31 box-sum + loss. TWO adjacent columns per thread:
// one ds_read2 + one funnel shift yields both columns' 31-bit windows
// (h(c0)=popc(w32&0x7FFFFFFF), h(c0+1)=popc(w32>>1)) -> per-pixel phase-B
// cost halves; pred loads are float2. Block = 512 thr = 2 row-groups x 256
// col-pairs, BAND=16. Grid 32x16=512 blocks, 2/CU, 16 waves/CU @ <=128 VGPR.
// ---------------------------------------------------------------------------
__global__ __launch_bounds__(512, 4) void mega_kernel(const uint32_t* __restrict__ bm,
                                                      const float* __restrict__ pred,
                                                      float* __restrict__ part) {
    __shared__ uint32_t B[HALO][WPR];
    const int tid = threadIdx.x;
    const int band = blockIdx.x;                 // 0..31
    const int n = blockIdx.y;
    const int r0 = band * BAND;
    const int cg = tid & 255, rg = tid >> 8;     // col-pair, row-group
    const int c0 = cg * 2;

    // ---- bitmap halo staging: 46 rows x 16 words = 736 loads ----
    const uint32_t* __restrict__ bmn = bm + (size_t)n * H_DIM * WROW;
    const int hrA = tid >> 4, wiA = tid & 15;    // rows 0..31
    const int ra = r0 - PADR + hrA;
    uint32_t wA = 0, wB = 0;
    if (ra >= 0 && ra < H_DIM) wA = bmn[ra * WROW + wiA];
    const int hrB = 32 + (tid >> 4);             // rows 32..45 (tid < 224)
    const int rb = r0 - PADR + hrB;
    if (tid < 224 && rb >= 0 && rb < H_DIM) wB = bmn[rb * WROW + wiA];

    // ---- pred float2 loads issued early (outstanding across phase B) ----
    const size_t img = (size_t)n * H_DIM * W_DIM;
    const float* __restrict__ p0 = pred + img * 2 + (size_t)(r0 + rg * 8) * W_DIM + c0;
    const float* __restrict__ p1 = p0 + (size_t)H_DIM * W_DIM;
    float2 x0[8], x1[8];
#pragma unroll
    for (int rr = 0; rr < 8; ++rr) {
        x0[rr] = *reinterpret_cast<const float2*>(p0 + rr * W_DIM);
        x1[rr] = *reinterpret_cast<const float2*>(p1 + rr * W_DIM);
    }

    // ---- LDS writes (wait only on bitmap loads; pred stays in flight) ----
    if (tid < 2 * HALO) B[tid >> 1][(tid & 1) ? (WPR - 1) : 0] = 0u;
    B[hrA][1 + wiA] = wA;
    if (tid < 224) B[hrB][1 + wiA] = wB;
    __syncthreads();

    // ---- phase B: 38 halo rows for this row-group; 2 cols per extraction ----
    const int b0 = c0 + (32 - PADR);             // window start bit for col c0
    const int q = b0 >> 5, s = b0 & 31;
    uint32_t run0 = 0, run1 = 0, mb0 = 0, mb1 = 0;
    uint32_t hlo0[7], hlo1[7], hhi0[7], hhi1[7];
#pragma unroll
    for (int i = 0; i < 38; ++i) {
        const int j = rg * 8 + i;
        const uint32_t lo = B[j][q];
        const uint32_t hi = B[j][q + 1];
        const uint32_t w32 = (uint32_t)((((uint64_t)hi << 32) | lo) >> s);
        const uint32_t h0 = (uint32_t)__popc(w32 & 0x7FFFFFFFu);
        const uint32_t h1 = (uint32_t)__popc(w32 >> 1);
        if (i < 31) { run0 += h0; run1 += h1; }
        if (i < 7) { hlo0[i] = h0; hlo1[i] = h1; }
        if (i >= 31) { hhi0[i - 31] = h0; hhi1[i - 31] = h1; }
        if (i >= PADR && i < PADR + 8) {         // center bits for output rows
            mb0 |= ((w32 >> 15) & 1u) << (i - PADR);
            mb1 |= ((w32 >> 16) & 1u) << (i - PADR);
        }
    }

    // ---- register pin: pred + slide-h must be materialized HERE ----
#pragma unroll
    for (int rr = 0; rr < 8; ++rr)
        asm volatile("" : "+v"(x0[rr].x), "+v"(x0[rr].y), "+v"(x1[rr].x), "+v"(x1[rr].y));
#pragma unroll
    for (int i = 0; i < 7; ++i)
        asm volatile("" : "+v"(hlo0[i]), "+v"(hlo1[i]), "+v"(hhi0[i]), "+v"(hhi1[i]));

    // ---- loss math: 8 rows x 2 cols x 2 channels ----
    const float cw0 = (float)(min(c0 + PADR, W_DIM - 1) - max(c0 - PADR, 0) + 1);
    const float cw1 = (float)(min(c0 + 1 + PADR, W_DIM - 1) - max(c0 + 1 - PADR, 0) + 1);
    const float inv961 = 1.0f / 961.0f;
    float bce = 0.f, in0 = 0.f, in1 = 0.f, un0 = 0.f, un1 = 0.f;

    auto docol = [&](float xc0, float xc1, uint32_t V, uint32_t mbit, float cnt) {
        const float m1 = (float)mbit;
        const float m0 = 1.0f - m1;
        const float box1 = (float)V * inv961;
        const float box0 = (cnt - (float)V) * inv961;
        const float w1f = 1.0f + 5.0f * fabsf(box1 - m1);
        const float w0f = 1.0f + 5.0f * fabsf(box0 - m0);
        {   // channel 0
            const float x = xc0;
            const float t = __expf(-fabsf(x));
            const float inv = __builtin_amdgcn_rcpf(1.0f + t);
            const float p = (x >= 0.f) ? inv : t * inv;
            bce += fmaxf(x, 0.f) - x * m0 + __logf(1.0f + t);
            in0 += p * m0 * w0f;
            un0 += (p + m0) * w0f;
        }
        {   // channel 1
            const float x = xc1;
            const float t = __expf(-fabsf(x));
            const float inv = __builtin_amdgcn_rcpf(1.0f + t);
            const float p = (x >= 0.f) ? inv : t * inv;
            bce += fmaxf(x, 0.f) - x * m1 + __logf(1.0f + t);
            in1 += p * m1 * w1f;
            un1 += (p + m1) * w1f;
        }
    };

#pragma unroll
    for (int rr = 0; rr < 8; ++rr) {
        const int r = r0 + rg * 8 + rr;
        const float cnth = (float)(min(r + PADR, H_DIM - 1) - max(r - PADR, 0) + 1);
        docol(x0[rr].x, x1[rr].x, run0, (mb0 >> rr) & 1u, cnth * cw0);
        docol(x0[rr].y, x1[rr].y, run1, (mb1 >> rr) & 1u, cnth * cw1);
        if (rr < 7) {                            // slide vertical window
            run0 += hhi0[rr] - hlo0[rr];
            run1 += hhi1[rr] - hlo1[rr];
        }
    }

    // ---- block reduction: 5 values -> plain store to private slot ----
    __shared__ float red[8 * 5];
    const int lane = tid & 63, wv = tid >> 6;
    float v[5] = {bce, in0, in1, un0, un1};
#pragma unroll
    for (int k = 0; k < 5; ++k)
#pragma unroll
        for (int off = 32; off > 0; off >>= 1)
            v[k] += __shfl_down(v[k], off);
    if (lane == 0)
#pragma unroll
        for (int k = 0; k < 5; ++k) red[wv * 5 + k] = v[k];
    __syncthreads();
    if (tid == 0) {
        float s2[5];
#pragma unroll
        for (int k = 0; k < 5; ++k) {
            s2[k] = red[k];
            for (int w2 = 1; w2 < 8; ++w2) s2[k] += red[w2 * 5 + k];
        }
        float* p = part + (size_t)(n * NBANDS + band) * 5;
#pragma unroll
        for (int k = 0; k < 5; ++k) p[k] = s2[k];
    }
}

// ---------------------------------------------------------------------------
// Finalize: reduce 512 block-partials -> out[0]. One block.
// 16 threads per image; each accumulates 2 partial rows.
// ---------------------------------------------------------------------------
__global__ __launch_bounds__(256) void finalize_kernel(const float* __restrict__ part,
                                                       float* __restrict__ out) {
    const int tid = threadIdx.x;   // 0..255
    const int n = tid >> 4;        // image
    const int i = tid & 15;
    float bce = 0.f, in0 = 0.f, in1 = 0.f, un0 = 0.f, un1 = 0.f;
#pragma unroll
    for (int j = 0; j < 2; ++j) {
        const float* p = part + (size_t)(n * NBANDS + j * 16 + i) * 5;
        bce += p[0]; in0 += p[1]; in1 += p[2]; un0 += p[3]; un1 += p[4];
    }
#pragma unroll
    for (int off = 8; off > 0; off >>= 1) {
        bce += __shfl_xor(bce, off, 16);
        in0 += __shfl_xor(in0, off, 16);
        in1 += __shfl_xor(in1, off, 16);
        un0 += __shfl_xor(un0, off, 16);
        un1 += __shfl_xor(un1, off, 16);
    }
    __shared__ float fb[16], fw[16];
    if (i == 0) {
        fb[n] = bce;
        fw[n] = (1.0f - (in0 + 1.0f) / (un0 - in0 + 1.0f)) +
                (1.0f - (in1 + 1.0f) / (un1 - in1 + 1.0f));
    }
    __syncthreads();
    if (tid == 0) {
        float sb = 0.f, sw = 0.f;
#pragma unroll
        for (int k = 0; k < 16; ++k) { sb += fb[k]; sw += fw[k]; }
        out[0] = sb / 8388608.0f + sw * (1.0f / 32.0f);  // 16*2*512*512 ; 32 (n,c) pairs
    }
}

extern "C" void kernel_launch(void* const* d_in, const int* in_sizes, int n_in,
                              void* d_out, int out_size, void* d_ws, size_t ws_size,
                              hipStream_t stream) {
    const float* pred = (const float*)d_in[0];
    const int* target = (const int*)d_in[1];
    float* part = (float*)d_ws;
    uint32_t* bm = (uint32_t*)((char*)d_ws + 32768);

    bitmap_kernel<<<2048, 256, 0, stream>>>((const int4*)target, bm);
    dim3 grid(NBANDS, N_IMG);
    mega_kernel<<<grid, 512, 0, stream>>>(bm, pred, part);
    finalize_kernel<<<1, 256, 0, stream>>>(part, (float*)d_out);
}

// Round 9
// 35.510 us; speedup vs baseline: 1.3193x; 1.3193x over previous
//
#include <hip/hip_runtime.h>
#include <stdint.h>

#define N_IMG 16
#define H_DIM 512
#define W_DIM 512
#define PADR 15
#define BAND 8                  // output rows per mega block
#define HALO (BAND + 2 * PADR)  // 38 halo rows
#define WPR 18                  // 32-bit words per bitmap row: 1 pad + 16 data + 1 pad
#define NBANDS (H_DIM / BAND)   // 64

// ws layout (poison-safe: every word written before read, every launch):
//   part @ 0      : 1024 blocks * 5 f32  [bce,in0,in1,un0,un1]
//   hb   @ 32 KiB : uint8 hb[N][512][512] = h(r,c) | m(r,c)<<7
//     h = 31-bit horizontal window popcount of (target==1), zero-padded
//     m = (target==1) at the pixel

// ---------------------------------------------------------------------------
// Stage 1: target -> per-pixel horizontal window popcount byte image.
// int4 x2 per thread (8 px), ballot-free word assembly via 2 shfl_xor merges;
// words staged in LDS (block = 4 full rows), then each thread funnels its own
// 8 pixels' windows and stores one coalesced 8-byte chunk. Horizontal work is
// done ONCE per pixel here (mega previously redid it 4.75x per halo overlap).
// ---------------------------------------------------------------------------
__global__ __launch_bounds__(256) void hrow_kernel(const int4* __restrict__ tg4,
                                                   uint8_t* __restrict__ hb) {
    __shared__ uint32_t B[4][WPR];               // 4 rows x (pad+16+pad) words
    const int tid = threadIdx.x;
    const size_t t = (size_t)blockIdx.x * 256 + tid;   // 8 ints per thread
    const int4 a = tg4[t * 2];
    const int4 b4 = tg4[t * 2 + 1];
    const uint32_t by = (uint32_t)(a.x == 1) | ((uint32_t)(a.y == 1) << 1) |
                        ((uint32_t)(a.z == 1) << 2) | ((uint32_t)(a.w == 1) << 3) |
                        ((uint32_t)(b4.x == 1) << 4) | ((uint32_t)(b4.y == 1) << 5) |
                        ((uint32_t)(b4.z == 1) << 6) | ((uint32_t)(b4.w == 1) << 7);
    uint32_t w = by << (8 * (tid & 3));
    w |= __shfl_xor(w, 1);
    w |= __shfl_xor(w, 2);
    if (tid < 8) B[tid >> 1][(tid & 1) ? (WPR - 1) : 0] = 0u;
    const int widx = tid >> 2;                   // 0..63 = row*16 + wordcol
    if ((tid & 3) == 0) B[widx >> 4][1 + (widx & 15)] = w;
    __syncthreads();

    // 8 pixels: row = p0>>9 (0..3), cols c0..c0+7. Window of col c starts at
    // bit c+17 (incl. 32-bit zero pad word); spans <= 2 words (s0 max 25).
    const int p0 = tid * 8;
    const int row = p0 >> 9;
    const int c0 = p0 & 511;
    const int bb = c0 + 17;
    const int q = bb >> 5, s0 = bb & 31;
    const uint32_t lo = B[row][q], hi = B[row][q + 1];
    const uint64_t dw = ((uint64_t)hi << 32) | lo;
    uint32_t pk0 = 0, pk1 = 0;
#pragma unroll
    for (int k = 0; k < 4; ++k) {
        const uint32_t v0 = (uint32_t)(dw >> (s0 + k)) & 0x7FFFFFFFu;
        const uint32_t v1 = (uint32_t)(dw >> (s0 + 4 + k)) & 0x7FFFFFFFu;
        pk0 |= ((uint32_t)__popc(v0) | (((by >> k) & 1u) << 7)) << (8 * k);
        pk1 |= ((uint32_t)__popc(v1) | (((by >> (4 + k)) & 1u) << 7)) << (8 * k);
    }
    *reinterpret_cast<uint2*>(hb + (size_t)blockIdx.x * 2048 + p0) =
        make_uint2(pk0, pk1);
}

// ---------------------------------------------------------------------------
// Stage 2: vertical 31-sum of h bytes + loss. NO bitmap LDS, NO barrier
// before the reduction: per thread, 38 coalesced byte loads down its column
// (hb is L2-resident, re-read 4.75x at 64B/wave/row), run = sum(b&0x7F),
// m from bit 7, slide = 2 ANDs. Block = 512 thr (one per col) x 8 rows;
// grid 64x16 = 1024 blocks -> 4/CU, 32 waves/CU at 64 VGPR.
// ---------------------------------------------------------------------------
__global__ __launch_bounds__(512, 8) void mega_kernel(const uint8_t* __restrict__ hb,
                                                      const float* __restrict__ pred,
                                                      float* __restrict__ part) {
    const int tid = threadIdx.x;                 // = col
    const int band = blockIdx.x;                 // 0..63
    const int n = blockIdx.y;
    const int r0 = band * BAND;
    const int col = tid;
    const uint8_t* __restrict__ hn = hb + (size_t)n * H_DIM * W_DIM;

    // ---- 38 vertical h-bytes (wave-uniform row validity) ----
    uint32_t bv[HALO];
#pragma unroll
    for (int i = 0; i < HALO; ++i) {
        const int r = r0 - PADR + i;
        bv[i] = (r >= 0 && r < H_DIM) ? (uint32_t)hn[(size_t)r * W_DIM + col] : 0u;
    }

    // ---- pred loads issued early (outstanding across phase B) ----
    const size_t img = (size_t)n * H_DIM * W_DIM;
    const float* __restrict__ p0 = pred + img * 2 + (size_t)r0 * W_DIM + col;
    const float* __restrict__ p1 = p0 + (size_t)H_DIM * W_DIM;
    float x0[BAND], x1[BAND];
#pragma unroll
    for (int rr = 0; rr < BAND; ++rr) {
        x0[rr] = p0[rr * W_DIM];
        x1[rr] = p1[rr * W_DIM];
    }

    // ---- initial vertical window + center m bits ----
    uint32_t run = 0, mbits = 0;
#pragma unroll
    for (int i = 0; i < 31; ++i) run += bv[i] & 0x7Fu;
#pragma unroll
    for (int rr = 0; rr < BAND; ++rr) mbits |= (bv[PADR + rr] >> 7) << rr;

    // ---- register pin: pred values materialized here (R5/R7 lesson) ----
#pragma unroll
    for (int rr = 0; rr < BAND; ++rr) asm volatile("" : "+v"(x0[rr]), "+v"(x1[rr]));

    // ---- loss math ----
    const int cntw = min(col + PADR, W_DIM - 1) - max(col - PADR, 0) + 1;
    const float inv961 = 1.0f / 961.0f;
    float bce = 0.f, in0 = 0.f, in1 = 0.f, un0 = 0.f, un1 = 0.f;

#pragma unroll
    for (int rr = 0; rr < BAND; ++rr) {
        const int r = r0 + rr;
        const int cnth = min(r + PADR, H_DIM - 1) - max(r - PADR, 0) + 1;
        const float cnt = (float)(cnth * cntw);
        const float m1 = (float)((mbits >> rr) & 1u);
        const float m0 = 1.0f - m1;
        const float V = (float)run;
        const float box1 = V * inv961;
        const float box0 = (cnt - V) * inv961;
        const float w1f = 1.0f + 5.0f * fabsf(box1 - m1);
        const float w0f = 1.0f + 5.0f * fabsf(box0 - m0);
        {   // channel 0
            const float x = x0[rr];
            const float t = __expf(-fabsf(x));
            const float inv = __builtin_amdgcn_rcpf(1.0f + t);   // v_rcp_f32
            const float p = (x >= 0.f) ? inv : t * inv;
            bce += fmaxf(x, 0.f) - x * m0 + __logf(1.0f + t);
            in0 += p * m0 * w0f;
            un0 += (p + m0) * w0f;
        }
        {   // channel 1
            const float x = x1[rr];
            const float t = __expf(-fabsf(x));
            const float inv = __builtin_amdgcn_rcpf(1.0f + t);
            const float p = (x >= 0.f) ? inv : t * inv;
            bce += fmaxf(x, 0.f) - x * m1 + __logf(1.0f + t);
            in1 += p * m1 * w1f;
            un1 += (p + m1) * w1f;
        }
        if (rr < BAND - 1)   // slide vertical window: registers only
            run += (bv[rr + 31] & 0x7Fu) - (bv[rr] & 0x7Fu);
    }

    // ---- block reduction: 5 values -> plain store to private slot ----
    __shared__ float red[8 * 5];
    const int lane = tid & 63, wv = tid >> 6;
    float v[5] = {bce, in0, in1, un0, un1};
#pragma unroll
    for (int k = 0; k < 5; ++k)
#pragma unroll
        for (int off = 32; off > 0; off >>= 1)
            v[k] += __shfl_down(v[k], off);
    if (lane == 0)
#pragma unroll
        for (int k = 0; k < 5; ++k) red[wv * 5 + k] = v[k];
    __syncthreads();
    if (tid == 0) {
        float s2[5];
#pragma unroll
        for (int k = 0; k < 5; ++k) {
            s2[k] = red[k];
            for (int w2 = 1; w2 < 8; ++w2) s2[k] += red[w2 * 5 + k];
        }
        float* p = part + (size_t)(n * NBANDS + band) * 5;
#pragma unroll
        for (int k = 0; k < 5; ++k) p[k] = s2[k];
    }
}

// ---------------------------------------------------------------------------
// Finalize: reduce 1024 block-partials -> out[0]. One block.
// 16 threads per image; each accumulates 4 partial rows.
// ---------------------------------------------------------------------------
__global__ __launch_bounds__(256) void finalize_kernel(const float* __restrict__ part,
                                                       float* __restrict__ out) {
    const int tid = threadIdx.x;   // 0..255
    const int n = tid >> 4;        // image
    const int i = tid & 15;
    float bce = 0.f, in0 = 0.f, in1 = 0.f, un0 = 0.f, un1 = 0.f;
#pragma unroll
    for (int j = 0; j < 4; ++j) {
        const float* p = part + (size_t)(n * NBANDS + j * 16 + i) * 5;
        bce += p[0]; in0 += p[1]; in1 += p[2]; un0 += p[3]; un1 += p[4];
    }
#pragma unroll
    for (int off = 8; off > 0; off >>= 1) {
        bce += __shfl_xor(bce, off, 16);
        in0 += __shfl_xor(in0, off, 16);
        in1 += __shfl_xor(in1, off, 16);
        un0 += __shfl_xor(un0, off, 16);
        un1 += __shfl_xor(un1, off, 16);
    }
    __shared__ float fb[16], fw[16];
    if (i == 0) {
        fb[n] = bce;
        fw[n] = (1.0f - (in0 + 1.0f) / (un0 - in0 + 1.0f)) +
                (1.0f - (in1 + 1.0f) / (un1 - in1 + 1.0f));
    }
    __syncthreads();
    if (tid == 0) {
        float sb = 0.f, sw = 0.f;
#pragma unroll
        for (int k = 0; k < 16; ++k) { sb += fb[k]; sw += fw[k]; }
        out[0] = sb / 8388608.0f + sw * (1.0f / 32.0f);  // 16*2*512*512 ; 32 (n,c) pairs
    }
}

extern "C" void kernel_launch(void* const* d_in, const int* in_sizes, int n_in,
                              void* d_out, int out_size, void* d_ws, size_t ws_size,
                              hipStream_t stream) {
    const float* pred = (const float*)d_in[0];
    const int* target = (const int*)d_in[1];
    float* part = (float*)d_ws;
    uint8_t* hb = (uint8_t*)d_ws + 32768;

    hrow_kernel<<<2048, 256, 0, stream>>>((const int4*)target, hb);
    dim3 grid(NBANDS, N_IMG);
    mega_kernel<<<grid, 512, 0, stream>>>(hb, pred, part);
    finalize_kernel<<<1, 256, 0, stream>>>(part, (float*)d_out);
}

// Round 10
// 28.885 us; speedup vs baseline: 1.6219x; 1.2294x over previous
//
#include <hip/hip_runtime.h>
#include <stdint.h>

#define N_IMG 16
#define H_DIM 512
#define W_DIM 512
#define PADR 15
#define BAND 8                  // output rows per mega block
#define WPR 18                  // 32-bit words per bitmap row: 1 pad + 16 data + 1 pad
#define NBANDS (H_DIM / BAND)   // 64
#define NR4 (H_DIM / 4)         // 128 packed row-groups per image

// ws layout (poison-safe: every word written before read, every launch):
//   part @ 0      : 1024 blocks * 5 f32  [bce,in0,in1,un0,un1]
//   vhb  @ 32 KiB : uint32 vhb[N][128][512]
//     byte r of vhb[n][g][c] = h(4g+r, c) | m(4g+r, c)<<7
//     h = 31-wide horizontal window popcount of (target==1), zero-padded (<=31)
//     m = (target==1) at the pixel

// ---------------------------------------------------------------------------
// Stage 1: target -> vertically-packed horizontal-popcount image.
// Block = 4 full rows (2048 px, 256 thr x 8 px). Row bitmaps assembled via
// shfl merges -> LDS; each thread funnels its 8 windows (h|m bytes), writes
// them to an LDS byte pane; after barrier, threads emit the 4-row vertical
// packs for 2 columns each (coalesced uint2 stores).
// ---------------------------------------------------------------------------
__global__ __launch_bounds__(256) void hrow_kernel(const int4* __restrict__ tg4,
                                                   uint32_t* __restrict__ vhb) {
    __shared__ uint32_t B[4][WPR];               // 4 rows x (pad+16+pad) bitmap words
    __shared__ uint32_t hL[4][128];              // 4 rows x 512 h-bytes
    const int tid = threadIdx.x;
    const size_t t = (size_t)blockIdx.x * 256 + tid;   // 8 ints per thread
    const int4 a = tg4[t * 2];
    const int4 b4 = tg4[t * 2 + 1];
    const uint32_t by = (uint32_t)(a.x == 1) | ((uint32_t)(a.y == 1) << 1) |
                        ((uint32_t)(a.z == 1) << 2) | ((uint32_t)(a.w == 1) << 3) |
                        ((uint32_t)(b4.x == 1) << 4) | ((uint32_t)(b4.y == 1) << 5) |
                        ((uint32_t)(b4.z == 1) << 6) | ((uint32_t)(b4.w == 1) << 7);
    uint32_t w = by << (8 * (tid & 3));
    w |= __shfl_xor(w, 1);
    w |= __shfl_xor(w, 2);
    if (tid < 8) B[tid >> 1][(tid & 1) ? (WPR - 1) : 0] = 0u;
    const int widx = tid >> 2;                   // 0..63 = row*16 + wordcol
    if ((tid & 3) == 0) B[widx >> 4][1 + (widx & 15)] = w;
    __syncthreads();

    // 8 windows: row = tid>>6, cols c0..c0+7; start bit of col c is c+17.
    const int row = tid >> 6;
    const int c0 = (tid & 63) * 8;
    const int bb = c0 + 17;
    const int q = bb >> 5, s0 = bb & 31;         // s0 <= 25 -> fits 64-bit funnel
    const uint32_t lo = B[row][q], hi = B[row][q + 1];
    const uint64_t dw = ((uint64_t)hi << 32) | lo;
    uint32_t pk0 = 0, pk1 = 0;
#pragma unroll
    for (int k = 0; k < 4; ++k) {
        const uint32_t v0 = (uint32_t)(dw >> (s0 + k)) & 0x7FFFFFFFu;
        const uint32_t v1 = (uint32_t)(dw >> (s0 + 4 + k)) & 0x7FFFFFFFu;
        pk0 |= ((uint32_t)__popc(v0) | (((by >> k) & 1u) << 7)) << (8 * k);
        pk1 |= ((uint32_t)__popc(v1) | (((by >> (4 + k)) & 1u) << 7)) << (8 * k);
    }
    hL[row][c0 >> 2] = pk0;
    hL[row][(c0 >> 2) + 1] = pk1;
    __syncthreads();

    // transpose: thread t emits columns 2t, 2t+1 (same source dword index)
    const int c = 2 * tid;
    const int di = c >> 2;
    const int sh = 8 * (c & 3);                  // 0 or 16
    const uint32_t w0 = hL[0][di], w1 = hL[1][di], w2 = hL[2][di], w3 = hL[3][di];
    const uint32_t outA = ((w0 >> sh) & 0xFFu) | (((w1 >> sh) & 0xFFu) << 8) |
                          (((w2 >> sh) & 0xFFu) << 16) | (((w3 >> sh) & 0xFFu) << 24);
    const uint32_t outB = ((w0 >> (sh + 8)) & 0xFFu) | (((w1 >> (sh + 8)) & 0xFFu) << 8) |
                          (((w2 >> (sh + 8)) & 0xFFu) << 16) |
                          (((w3 >> (sh + 8)) & 0xFFu) << 24);
    *reinterpret_cast<uint2*>(vhb + (size_t)blockIdx.x * 512 + c) =
        make_uint2(outA, outB);
}

// ---------------------------------------------------------------------------
// Stage 2: vertical 31-sum over packed h-dwords + loss. Per thread (= one
// column): 10 coalesced dword loads cover all 38 halo rows; initial window
// via byte-SIMD sum (bytes <= 248, no carry) + one horizontal byte sum;
// slide = 2 byte extracts. No bitmap LDS, no staging barrier. ~50 live VGPRs
// -> fits the 64-VGPR ceiling (R8/R9 failure mode avoided by design).
// Grid 64x16 = 1024 blocks -> 4/CU, 32 waves/CU.
// ---------------------------------------------------------------------------
__global__ __launch_bounds__(512, 8) void mega_kernel(const uint32_t* __restrict__ vhb,
                                                      const float* __restrict__ pred,
                                                      float* __restrict__ part) {
    const int tid = threadIdx.x;                 // = col
    const int band = blockIdx.x;                 // 0..63
    const int n = blockIdx.y;
    const int r0 = band * BAND;
    const int col = tid;
    const int g_base = band * 2 - 4;             // r0/4 - 4
    const uint32_t* __restrict__ vn = vhb + (size_t)n * NR4 * W_DIM;

    // ---- 10 packed group loads (wave-uniform validity, coalesced) ----
    uint32_t G[10];
#pragma unroll
    for (int k = 0; k < 10; ++k) {
        const int g = g_base + k;
        G[k] = (g >= 0 && g < NR4) ? vn[(size_t)g * W_DIM + col] : 0u;
    }

    // ---- pred loads issued early (outstanding across the vertical phase) ----
    const size_t img = (size_t)n * H_DIM * W_DIM;
    const float* __restrict__ p0 = pred + img * 2 + (size_t)r0 * W_DIM + col;
    const float* __restrict__ p1 = p0 + (size_t)H_DIM * W_DIM;
    float x0[BAND], x1[BAND];
#pragma unroll
    for (int rr = 0; rr < BAND; ++rr) {
        x0[rr] = p0[rr * W_DIM];
        x1[rr] = p1[rr * W_DIM];
    }

    // ---- masked h planes + initial vertical window (rows r0-15..r0+15) ----
    uint32_t M[10];
#pragma unroll
    for (int k = 0; k < 10; ++k) M[k] = G[k] & 0x1F1F1F1Fu;
    uint32_t S = M[0] & 0xFFFFFF00u;             // group0: drop row r0-16
#pragma unroll
    for (int k = 1; k < 8; ++k) S += M[k];       // bytewise sums <= 248: no carry
    const uint32_t hw = (S & 0x00FF00FFu) + ((S >> 8) & 0x00FF00FFu);
    uint32_t run = (hw + (hw >> 16)) & 0x3FFu;

    // ---- register pin: pred values materialized here (R5/R7 lesson) ----
#pragma unroll
    for (int rr = 0; rr < BAND; ++rr) asm volatile("" : "+v"(x0[rr]), "+v"(x1[rr]));

    // ---- loss math ----
    const int cntw = min(col + PADR, W_DIM - 1) - max(col - PADR, 0) + 1;
    const float inv961 = 1.0f / 961.0f;
    float bce = 0.f, in0 = 0.f, in1 = 0.f, un0 = 0.f, un1 = 0.f;

#pragma unroll
    for (int rr = 0; rr < BAND; ++rr) {
        const int r = r0 + rr;
        const int cnth = min(r + PADR, H_DIM - 1) - max(r - PADR, 0) + 1;
        const float cnt = (float)(cnth * cntw);
        const float m1 = (float)((G[4 + (rr >> 2)] >> (8 * (rr & 3) + 7)) & 1u);
        const float m0 = 1.0f - m1;
        const float V = (float)run;
        const float box1 = V * inv961;
        const float box0 = (cnt - V) * inv961;
        const float w1f = 1.0f + 5.0f * fabsf(box1 - m1);
        const float w0f = 1.0f + 5.0f * fabsf(box0 - m0);
        {   // channel 0
            const float x = x0[rr];
            const float t = __expf(-fabsf(x));
            const float inv = __builtin_amdgcn_rcpf(1.0f + t);   // v_rcp_f32
            const float p = (x >= 0.f) ? inv : t * inv;
            bce += fmaxf(x, 0.f) - x * m0 + __logf(1.0f + t);
            in0 += p * m0 * w0f;
            un0 += (p + m0) * w0f;
        }
        {   // channel 1
            const float x = x1[rr];
            const float t = __expf(-fabsf(x));
            const float inv = __builtin_amdgcn_rcpf(1.0f + t);
            const float p = (x >= 0.f) ? inv : t * inv;
            bce += fmaxf(x, 0.f) - x * m1 + __logf(1.0f + t);
            in1 += p * m1 * w1f;
            un1 += (p + m1) * w1f;
        }
        if (rr < BAND - 1) {   // slide: +row r0+16+rr, -row r0-15+rr (imm shifts)
            const uint32_t addv = (M[8 + (rr >> 2)] >> (8 * (rr & 3))) & 0xFFu;
            const uint32_t subv = (M[(1 + rr) >> 2] >> (8 * ((1 + rr) & 3))) & 0xFFu;
            run += addv - subv;
        }
    }

    // ---- block reduction: 5 values -> plain store to private slot ----
    __shared__ float red[8 * 5];
    const int lane = tid & 63, wv = tid >> 6;
    float v[5] = {bce, in0, in1, un0, un1};
#pragma unroll
    for (int k = 0; k < 5; ++k)
#pragma unroll
        for (int off = 32; off > 0; off >>= 1)
            v[k] += __shfl_down(v[k], off);
    if (lane == 0)
#pragma unroll
        for (int k = 0; k < 5; ++k) red[wv * 5 + k] = v[k];
    __syncthreads();
    if (tid == 0) {
        float s2[5];
#pragma unroll
        for (int k = 0; k < 5; ++k) {
            s2[k] = red[k];
            for (int w2 = 1; w2 < 8; ++w2) s2[k] += red[w2 * 5 + k];
        }
        float* p = part + (size_t)(n * NBANDS + band) * 5;
#pragma unroll
        for (int k = 0; k < 5; ++k) p[k] = s2[k];
    }
}

// ---------------------------------------------------------------------------
// Finalize: reduce 1024 block-partials -> out[0]. One block.
// 16 threads per image; each accumulates 4 partial rows.
// ---------------------------------------------------------------------------
__global__ __launch_bounds__(256) void finalize_kernel(const float* __restrict__ part,
                                                       float* __restrict__ out) {
    const int tid = threadIdx.x;   // 0..255
    const int n = tid >> 4;        // image
    const int i = tid & 15;
    float bce = 0.f, in0 = 0.f, in1 = 0.f, un0 = 0.f, un1 = 0.f;
#pragma unroll
    for (int j = 0; j < 4; ++j) {
        const float* p = part + (size_t)(n * NBANDS + j * 16 + i) * 5;
        bce += p[0]; in0 += p[1]; in1 += p[2]; un0 += p[3]; un1 += p[4];
    }
#pragma unroll
    for (int off = 8; off > 0; off >>= 1) {
        bce += __shfl_xor(bce, off, 16);
        in0 += __shfl_xor(in0, off, 16);
        in1 += __shfl_xor(in1, off, 16);
        un0 += __shfl_xor(un0, off, 16);
        un1 += __shfl_xor(un1, off, 16);
    }
    __shared__ float fb[16], fw[16];
    if (i == 0) {
        fb[n] = bce;
        fw[n] = (1.0f - (in0 + 1.0f) / (un0 - in0 + 1.0f)) +
                (1.0f - (in1 + 1.0f) / (un1 - in1 + 1.0f));
    }
    __syncthreads();
    if (tid == 0) {
        float sb = 0.f, sw = 0.f;
#pragma unroll
        for (int k = 0; k < 16; ++k) { sb += fb[k]; sw += fw[k]; }
        out[0] = sb / 8388608.0f + sw * (1.0f / 32.0f);  // 16*2*512*512 ; 32 (n,c) pairs
    }
}

extern "C" void kernel_launch(void* const* d_in, const int* in_sizes, int n_in,
                              void* d_out, int out_size, void* d_ws, size_t ws_size,
                              hipStream_t stream) {
    const float* pred = (const float*)d_in[0];
    const int* target = (const int*)d_in[1];
    float* part = (float*)d_ws;
    uint32_t* vhb = (uint32_t*)((char*)d_ws + 32768);

    hrow_kernel<<<2048, 256, 0, stream>>>((const int4*)target, vhb);
    dim3 grid(NBANDS, N_IMG);
    mega_kernel<<<grid, 512, 0, stream>>>(vhb, pred, part);
    finalize_kernel<<<1, 256, 0, stream>>>(part, (float*)d_out);
}